// Round 10
// baseline (2801.796 us; speedup 1.0000x reference)
//
#include <hip/hip_runtime.h>
#include <hip/hip_bf16.h>

// LSMPool round 10: NULL EXPERIMENT — measure per-dispatch overhead.
//   Round-9 pipeline kept byte-for-byte identical; added k_nop (empty,
//   grid 256x256) after each step's reduce = +128 pure-overhead dispatches.
//   dur_us delta vs round 9 (2517us) / 128 = marginal in-graph launch cost.
//   This forks round 11: merge-to-1-launch/persistent (if Δ large) vs
//   byte-reduction (if Δ ~ 0).

namespace {
constexpr int T_STEPS = 128;
constexpr int BATCH   = 64;
constexpr int IN_F    = 1024;
constexpr int HID     = 4096;
constexpr int OUT_F   = 512;
constexpr int TOTAL   = IN_F + HID;    // 5120
constexpr int BK      = 64;
constexpr int NCH     = 64;            // n-chunks of 64
constexpr int KSPL    = 8;
constexpr int KRANGE  = TOTAL / KSPL;  // 640
constexpr int NWIN    = KRANGE / BK;   // 10
constexpr int BUFB    = 24576;         // A 8K | Bh 8K | Bl 8K
constexpr int NBUF    = 3;             // 73728 B LDS (2 blocks/CU = 144K)
}

using bf16x8 = __attribute__((ext_vector_type(8))) short;
using f32x4  = __attribute__((ext_vector_type(4))) float;

__device__ __forceinline__ void gload_lds16(const void* g, void* l) {
  __builtin_amdgcn_global_load_lds(
      (const __attribute__((address_space(1))) unsigned int*)(g),
      (__attribute__((address_space(3))) unsigned int*)(l), 16, 0, 0);
}

// ---------------- null-experiment kernel ----------------
__global__ void k_nop() {}

// ---------------- prep kernels ----------------

__global__ void k_cvt_split(const float* __restrict__ src,
                            __hip_bfloat16* __restrict__ hi,
                            __hip_bfloat16* __restrict__ lo, int n4) {
  int i = blockIdx.x * blockDim.x + threadIdx.x;
  if (i >= n4) return;
  float4 v = reinterpret_cast<const float4*>(src)[i];
#define CVT1(J, F)                                                        \
  {                                                                       \
    __hip_bfloat16 hb = __float2bfloat16(F);                              \
    hi[4 * (size_t)i + J] = hb;                                           \
    lo[4 * (size_t)i + J] = __float2bfloat16((F) - __bfloat162float(hb)); \
  }
  CVT1(0, v.x) CVT1(1, v.y) CVT1(2, v.z) CVT1(3, v.w)
#undef CVT1
}

__global__ void k_cvt_x(const float* __restrict__ src,
                        __hip_bfloat16* __restrict__ dst, int n) {
  int i = blockIdx.x * blockDim.x + threadIdx.x;
  if (i >= n) return;
  dst[i] = __float2bfloat16(src[i]);
}

__global__ void k_zero(float* __restrict__ mem1, ushort* __restrict__ spk0, int n) {
  int i = blockIdx.x * blockDim.x + threadIdx.x;
  if (i >= n) return;
  mem1[i] = 0.0f;
  spk0[i] = 0;  // bf16 +0.0
}

// ---------------- fc1 K-split GEMM (round-9 verbatim) ----------------
__global__ __launch_bounds__(256, 2)
void k_fc1(int t,
           const __hip_bfloat16* __restrict__ xb,    // [T][B][IN_F]
           const __hip_bfloat16* __restrict__ spk,   // [T+1][B][HID]
           const __hip_bfloat16* __restrict__ w1hi,  // [HID][TOTAL]
           const __hip_bfloat16* __restrict__ w1lo,
           float* __restrict__ part) {               // [KSPL][B][HID]
  __shared__ __align__(16) char smem[NBUF * BUFB];

  const int tid = threadIdx.x;
  const int l   = tid & 63;
  const int wv  = tid >> 6;
  const int nchunk = blockIdx.x & 63;
  const int ks     = blockIdx.x >> 6;
  const int nbase  = nchunk * 64;
  const int kbase  = ks * KRANGE;

  const __hip_bfloat16* xbt  = xb  + (size_t)t * BATCH * IN_F;
  const __hip_bfloat16* spkt = spk + (size_t)t * BATCH * HID;

  const int row8 = l >> 3;
  const int cswz = ((l & 7) ^ row8) * 8;
  const int s0 = 2 * wv, s1 = 2 * wv + 1;
  const int rA0 = s0 * 8 + row8;
  const int rA1 = s1 * 8 + row8;

  const int fr  = l & 15;
  const int fks = l >> 4;
  const int f7  = fr & 7;

  f32x4 acc[4];
#pragma unroll
  for (int mf = 0; mf < 4; ++mf) acc[mf] = (f32x4){0.f, 0.f, 0.f, 0.f};

  auto ISSUE = [&](int iw, char* buf) {
    const int k0 = kbase + iw * BK;
    if (k0 < IN_F) {
      gload_lds16(xbt + (size_t)rA0 * IN_F + k0 + cswz, buf + s0 * 1024);
      gload_lds16(xbt + (size_t)rA1 * IN_F + k0 + cswz, buf + s1 * 1024);
    } else {
      const int kh = k0 - IN_F;
      gload_lds16(spkt + (size_t)rA0 * HID + kh + cswz, buf + s0 * 1024);
      gload_lds16(spkt + (size_t)rA1 * HID + kh + cswz, buf + s1 * 1024);
    }
    gload_lds16(w1hi + (size_t)(nbase + rA0) * TOTAL + k0 + cswz,
                buf + 8192 + s0 * 1024);
    gload_lds16(w1hi + (size_t)(nbase + rA1) * TOTAL + k0 + cswz,
                buf + 8192 + s1 * 1024);
    gload_lds16(w1lo + (size_t)(nbase + rA0) * TOTAL + k0 + cswz,
                buf + 16384 + s0 * 1024);
    gload_lds16(w1lo + (size_t)(nbase + rA1) * TOTAL + k0 + cswz,
                buf + 16384 + s1 * 1024);
  };

  auto COMP = [&](const char* buf) {
    const int browB = wv * 16 + fr;
#pragma unroll
    for (int s = 0; s < 2; ++s) {
      const int co = ((s * 4 + fks) ^ f7) * 16;
      bf16x8 bh = *(const bf16x8*)(buf + 8192  + browB * 128 + co);
      bf16x8 bl = *(const bf16x8*)(buf + 16384 + browB * 128 + co);
#pragma unroll
      for (int mf = 0; mf < 4; ++mf) {
        bf16x8 a = *(const bf16x8*)(buf + (mf * 16 + fr) * 128 + co);
        acc[mf] = __builtin_amdgcn_mfma_f32_16x16x32_bf16(a, bh, acc[mf], 0, 0, 0);
        acc[mf] = __builtin_amdgcn_mfma_f32_16x16x32_bf16(a, bl, acc[mf], 0, 0, 0);
      }
    }
  };

  ISSUE(0, smem);
  ISSUE(1, smem + BUFB);
  for (int i = 0; i < NWIN; ++i) {
    if (i + 1 < NWIN) {
      asm volatile("s_waitcnt vmcnt(6)" ::: "memory");
    } else {
      asm volatile("s_waitcnt vmcnt(0)" ::: "memory");
    }
    __builtin_amdgcn_s_barrier();
    asm volatile("" ::: "memory");
    const char* bufc = smem + (i % 3) * BUFB;
    COMP(bufc);
    if (i + 2 < NWIN) ISSUE(i + 2, smem + ((i + 2) % 3) * BUFB);
  }

  float* pp = part + (size_t)ks * (BATCH * HID) + nbase + wv * 16 + fr;
  const int brow = (l >> 4) * 4;
#pragma unroll
  for (int mf = 0; mf < 4; ++mf) {
#pragma unroll
    for (int q = 0; q < 4; ++q) {
      pp[(size_t)(mf * 16 + brow + q) * HID] = acc[mf][q];
    }
  }
}

// ---------------- fc1 partial-reduce + LIF (round-9 verbatim) -------------
__global__ __launch_bounds__(256)
void k_fc1_red(const float* __restrict__ part,   // [KSPL][B][HID]
               float* __restrict__ mem1,         // [B][HID]
               const float* __restrict__ beta,   // [HID]
               const float* __restrict__ thr,    // [HID]
               ushort* __restrict__ spk_out) {   // [B][HID] bf16 bits
  const int i0 = (blockIdx.x * 256 + threadIdx.x) * 4;
  constexpr int PS = BATCH * HID;  // 262144
  float4 c = *(const float4*)(part + i0);
#pragma unroll
  for (int k2 = 1; k2 < KSPL; ++k2) {
    const float4 p = *(const float4*)(part + (size_t)k2 * PS + i0);
    c.x += p.x; c.y += p.y; c.z += p.z; c.w += p.w;
  }

  const int n0 = i0 & (HID - 1);
  const float4 bt = *(const float4*)(beta + n0);
  const float4 th = *(const float4*)(thr + n0);
  float4 mv = *(float4*)(mem1 + i0);

  ushort4 so;
#define LIF1(COMP_M, COMP_B, COMP_T, SOUT)                  \
  {                                                         \
    float m2 = COMP_M - COMP_B + c.SOUT;                    \
    m2 = fmaxf(m2, 0.f);                                    \
    const bool sp = (m2 > COMP_T);                          \
    if (sp) m2 -= COMP_T;                                   \
    COMP_M = m2;                                            \
    so.SOUT = sp ? (ushort)0x3F80 : (ushort)0;              \
  }
  LIF1(mv.x, bt.x, th.x, x)
  LIF1(mv.y, bt.y, th.y, y)
  LIF1(mv.z, bt.z, th.z, z)
  LIF1(mv.w, bt.w, th.w, w)
#undef LIF1
  *(float4*)(mem1 + i0) = mv;
  *(ushort4*)(spk_out + i0) = so;
}

// ---------------- readout GEMM v2 (unchanged) ----------------
__global__ __launch_bounds__(256, 2)
void k_ro_gemm(const __hip_bfloat16* __restrict__ A,
               const __hip_bfloat16* __restrict__ w2hi,
               const __hip_bfloat16* __restrict__ w2lo,
               const float* __restrict__ b2,
               float* __restrict__ cur2) {
  __shared__ __align__(16) short lA[2][64 * BK];
  __shared__ __align__(16) short lBh[2][64 * BK];
  __shared__ __align__(16) short lBl[2][64 * BK];

  const int tid  = threadIdx.x;
  const int lane = tid & 63;
  const int w    = tid >> 6;

  const int xcd = blockIdx.x & 7;
  const int c   = blockIdx.x >> 3;
  const int mt  = xcd * 16 + (c >> 3);
  const int nt  = c & 7;
  const int mbase = mt * 64;
  const int nbase = nt * 64;

  const int rS   = tid >> 2;
  const int cEl  = (tid & 3) * 16;
  const int swzX = (rS & 7) << 4;
  const int stByte0 = rS * 128 + ((cEl * 2) ^ swzX);
  const int stByte1 = rS * 128 + ((cEl * 2 + 16) ^ swzX);

  const int fr    = lane & 15;
  const int fkB   = (lane >> 4) * 16;
  const int frSwz = (fr & 7) << 4;

  f32x4 acc[4];
#pragma unroll
  for (int m = 0; m < 4; ++m) acc[m] = (f32x4){0.f, 0.f, 0.f, 0.f};
  bf16x8 rgA[6], rgB[6];

  auto GLOAD = [&](int it, bf16x8* R) {
    const int k0 = it * BK;
    const __hip_bfloat16* asrc = A    + (size_t)(mbase + rS) * HID + k0 + cEl;
    const __hip_bfloat16* hsrc = w2hi + (size_t)(nbase + rS) * HID + k0 + cEl;
    const __hip_bfloat16* lsrc = w2lo + (size_t)(nbase + rS) * HID + k0 + cEl;
    R[0] = *(const bf16x8*)(asrc);
    R[1] = *(const bf16x8*)(asrc + 8);
    R[2] = *(const bf16x8*)(hsrc);
    R[3] = *(const bf16x8*)(hsrc + 8);
    R[4] = *(const bf16x8*)(lsrc);
    R[5] = *(const bf16x8*)(lsrc + 8);
  };
  auto DSWRITE = [&](int ibuf, bf16x8* R) {
    *(bf16x8*)((char*)lA[ibuf] + stByte0)  = R[0];
    *(bf16x8*)((char*)lA[ibuf] + stByte1)  = R[1];
    *(bf16x8*)((char*)lBh[ibuf] + stByte0) = R[2];
    *(bf16x8*)((char*)lBh[ibuf] + stByte1) = R[3];
    *(bf16x8*)((char*)lBl[ibuf] + stByte0) = R[4];
    *(bf16x8*)((char*)lBl[ibuf] + stByte1) = R[5];
  };
  auto COMPUTE = [&](int ibuf) {
    const char* pA  = (const char*)lA[ibuf];
    const char* pBh = (const char*)lBh[ibuf];
    const char* pBl = (const char*)lBl[ibuf];
#pragma unroll
    for (int s = 0; s < 2; ++s) {
      const int co = ((s * 64 + fkB) ^ frSwz);
      bf16x8 fbh = *(const bf16x8*)(pBh + (w * 16 + fr) * 128 + co);
      bf16x8 fbl = *(const bf16x8*)(pBl + (w * 16 + fr) * 128 + co);
#pragma unroll
      for (int m = 0; m < 4; ++m) {
        bf16x8 fa = *(const bf16x8*)(pA + (m * 16 + fr) * 128 + co);
        acc[m] = __builtin_amdgcn_mfma_f32_16x16x32_bf16(fa, fbh, acc[m], 0, 0, 0);
        acc[m] = __builtin_amdgcn_mfma_f32_16x16x32_bf16(fa, fbl, acc[m], 0, 0, 0);
      }
    }
  };

  constexpr int RNIT = HID / BK;  // 64
  GLOAD(0, rgA);
  DSWRITE(0, rgA);
  __syncthreads();
  for (int itp = 0; itp < RNIT / 2; ++itp) {
    const int it = itp * 2;
    GLOAD(it + 1, rgB);
    COMPUTE(0);
    DSWRITE(1, rgB);
    __syncthreads();
    if (it + 2 < RNIT) {
      GLOAD(it + 2, rgA);
      COMPUTE(1);
      DSWRITE(0, rgA);
      __syncthreads();
    } else {
      COMPUTE(1);
    }
  }

  const int col = nbase + w * 16 + fr;
  const float bias = b2[col];
  const int brow = (lane >> 4) * 4;
#pragma unroll
  for (int m = 0; m < 4; ++m) {
#pragma unroll
    for (int q = 0; q < 4; ++q) {
      const int row = mbase + m * 16 + brow + q;
      cur2[(size_t)row * OUT_F + col] = acc[m][q] + bias;
    }
  }
}

// ---------------- readout LIF scan ----------------
__global__ void k_ro_scan(const float* __restrict__ cur2,
                          const float* __restrict__ beta,
                          const float* __restrict__ thr,
                          float* __restrict__ out) {
  const int i = blockIdx.x * blockDim.x + threadIdx.x;
  const int b = i >> 9;
  const int o = i & (OUT_F - 1);
  const float bt = beta[o];
  const float th = thr[o];
  float m = 0.0f;
  for (int t = 0; t < T_STEPS; ++t) {
    const size_t idx = (size_t)(t * BATCH + b) * OUT_F + o;
    m = m - bt + cur2[idx];
    const float s = (m > th) ? 1.0f : 0.0f;
    m -= s * th;
    out[idx] = s;
  }
}

// ---------------- launch ----------------
extern "C" void kernel_launch(void* const* d_in, const int* in_sizes, int n_in,
                              void* d_out, int out_size, void* d_ws, size_t ws_size,
                              hipStream_t stream) {
  const float* x        = (const float*)d_in[0];
  const float* w1       = (const float*)d_in[1];
  const float* w2       = (const float*)d_in[2];
  const float* b2       = (const float*)d_in[3];
  const float* beta_lsm = (const float*)d_in[4];
  const float* thr_lsm  = (const float*)d_in[5];
  const float* beta_ro  = (const float*)d_in[6];
  const float* thr_ro   = (const float*)d_in[7];
  float* out = (float*)d_out;

  char* ws = (char*)d_ws;
  size_t off = 0;
  auto alloc = [&](size_t bytes) -> char* {
    char* p = ws + off;
    off += (bytes + 255) & ~(size_t)255;
    return p;
  };
  __hip_bfloat16* w1hi = (__hip_bfloat16*)alloc((size_t)HID * TOTAL * 2);
  __hip_bfloat16* w1lo = (__hip_bfloat16*)alloc((size_t)HID * TOTAL * 2);
  __hip_bfloat16* xb   = (__hip_bfloat16*)alloc((size_t)T_STEPS * BATCH * IN_F * 2);
  __hip_bfloat16* spk  = (__hip_bfloat16*)alloc((size_t)(T_STEPS + 1) * BATCH * HID * 2);
  __hip_bfloat16* w2hi = (__hip_bfloat16*)alloc((size_t)OUT_F * HID * 2);
  __hip_bfloat16* w2lo = (__hip_bfloat16*)alloc((size_t)OUT_F * HID * 2);
  float* mem1 = (float*)alloc((size_t)BATCH * HID * 4);
  float* cur2 = (float*)alloc((size_t)T_STEPS * BATCH * OUT_F * 4);
  float* part = cur2;   // aliased, disjoint lifetimes

  // prep
  {
    int n4 = HID * TOTAL / 4;
    k_cvt_split<<<(n4 + 255) / 256, 256, 0, stream>>>(w1, w1hi, w1lo, n4);
  }
  {
    int n4 = OUT_F * HID / 4;
    k_cvt_split<<<(n4 + 255) / 256, 256, 0, stream>>>(w2, w2hi, w2lo, n4);
  }
  {
    int n = T_STEPS * BATCH * IN_F;
    k_cvt_x<<<(n + 255) / 256, 256, 0, stream>>>(x, xb, n);
  }
  {
    int n = BATCH * HID;
    k_zero<<<(n + 255) / 256, 256, 0, stream>>>(mem1, (ushort*)spk, n);
  }

  // sequential reservoir steps + NULL-EXPERIMENT no-op dispatch per step
  for (int t = 0; t < T_STEPS; ++t) {
    k_fc1<<<NCH * KSPL, 256, 0, stream>>>(t, xb, spk, w1hi, w1lo, part);
    k_fc1_red<<<BATCH * HID / (256 * 4), 256, 0, stream>>>(
        part, mem1, beta_lsm, thr_lsm,
        (ushort*)(spk + (size_t)(t + 1) * BATCH * HID));
    k_nop<<<256, 256, 0, stream>>>();   // pure-overhead probe
  }

  // readout
  k_ro_gemm<<<(T_STEPS * BATCH / 64) * (OUT_F / 64), 256, 0, stream>>>(
      spk + (size_t)BATCH * HID, w2hi, w2lo, b2, cur2);
  k_ro_scan<<<(BATCH * OUT_F) / 256, 256, 0, stream>>>(cur2, beta_ro, thr_ro, out);
}

// Round 11
// 2451.801 us; speedup vs baseline: 1.1427x; 1.1427x over previous
//
#include <hip/hip_runtime.h>
#include <hip/hip_bf16.h>

// LSMPool round 11: remove the x-part from the sequential path.
//   r10 null experiment: in-graph dispatch ≈ 2.2us; step work ≈ 13us ≈
//   w1 84MB at ~6.5 TB/s -> w1-byte-bound. Precision is pinned (bf16 hi+lo),
//   so the only byte cut is structural: xcur[T][B][HID] = X @ w1x^T
//   precomputed as ONE parallel GEMM (M=8192,N=4096,K=1024, ro_gemm-v2
//   skeleton, L2-aware block decode). Steps then run K=4096 (w1h only,
//   67MB/step, NWIN=8); k_fc1_red seeds the reduce with the xcur slice.
//   k_fc1 generalized (runtime krange/nwin/kofs); if ws_size can't hold
//   xcur (134MB), falls back to the r9 path exactly (deterministic in ws).

namespace {
constexpr int T_STEPS = 128;
constexpr int BATCH   = 64;
constexpr int IN_F    = 1024;
constexpr int HID     = 4096;
constexpr int OUT_F   = 512;
constexpr int TOTAL   = IN_F + HID;    // 5120
constexpr int BK      = 64;
constexpr int NCH     = 64;            // n-chunks of 64
constexpr int KSPL    = 8;
constexpr int BUFB    = 24576;         // A 8K | Bh 8K | Bl 8K
constexpr int NBUF    = 3;             // 73728 B LDS (2 blocks/CU = 144K)
}

using bf16x8 = __attribute__((ext_vector_type(8))) short;
using f32x4  = __attribute__((ext_vector_type(4))) float;

__device__ __forceinline__ void gload_lds16(const void* g, void* l) {
  __builtin_amdgcn_global_load_lds(
      (const __attribute__((address_space(1))) unsigned int*)(g),
      (__attribute__((address_space(3))) unsigned int*)(l), 16, 0, 0);
}

// ---------------- prep kernels ----------------

__global__ void k_cvt_split(const float* __restrict__ src,
                            __hip_bfloat16* __restrict__ hi,
                            __hip_bfloat16* __restrict__ lo, int n4) {
  int i = blockIdx.x * blockDim.x + threadIdx.x;
  if (i >= n4) return;
  float4 v = reinterpret_cast<const float4*>(src)[i];
#define CVT1(J, F)                                                        \
  {                                                                       \
    __hip_bfloat16 hb = __float2bfloat16(F);                              \
    hi[4 * (size_t)i + J] = hb;                                           \
    lo[4 * (size_t)i + J] = __float2bfloat16((F) - __bfloat162float(hb)); \
  }
  CVT1(0, v.x) CVT1(1, v.y) CVT1(2, v.z) CVT1(3, v.w)
#undef CVT1
}

__global__ void k_cvt_x(const float* __restrict__ src,
                        __hip_bfloat16* __restrict__ dst, int n) {
  int i = blockIdx.x * blockDim.x + threadIdx.x;
  if (i >= n) return;
  dst[i] = __float2bfloat16(src[i]);
}

__global__ void k_zero(float* __restrict__ mem1, ushort* __restrict__ spk0, int n) {
  int i = blockIdx.x * blockDim.x + threadIdx.x;
  if (i >= n) return;
  mem1[i] = 0.0f;
  spk0[i] = 0;  // bf16 +0.0
}

// ---------------- fc1 K-split GEMM (r9 core, runtime K geometry) ----------
// block = (nchunk = blockIdx&63 -> N=64, ks = blockIdx>>6). kbase =
// kofs + ks*krange. xcur mode: kofs=IN_F, krange=512, nwin=8 (spk-only).
// fallback: kofs=0, krange=640, nwin=10 (r9 verbatim behavior).
__global__ __launch_bounds__(256, 2)
void k_fc1(int t,
           const __hip_bfloat16* __restrict__ xb,    // [T][B][IN_F]
           const __hip_bfloat16* __restrict__ spk,   // [T+1][B][HID]
           const __hip_bfloat16* __restrict__ w1hi,  // [HID][TOTAL]
           const __hip_bfloat16* __restrict__ w1lo,
           float* __restrict__ part,                 // [KSPL][B][HID]
           int krange, int nwin, int kofs) {
  __shared__ __align__(16) char smem[NBUF * BUFB];

  const int tid = threadIdx.x;
  const int l   = tid & 63;
  const int wv  = tid >> 6;
  const int nchunk = blockIdx.x & 63;
  const int ks     = blockIdx.x >> 6;
  const int nbase  = nchunk * 64;
  const int kbase  = kofs + ks * krange;

  const __hip_bfloat16* xbt  = xb  + (size_t)t * BATCH * IN_F;
  const __hip_bfloat16* spkt = spk + (size_t)t * BATCH * HID;

  const int row8 = l >> 3;
  const int cswz = ((l & 7) ^ row8) * 8;
  const int s0 = 2 * wv, s1 = 2 * wv + 1;
  const int rA0 = s0 * 8 + row8;
  const int rA1 = s1 * 8 + row8;

  const int fr  = l & 15;
  const int fks = l >> 4;
  const int f7  = fr & 7;

  f32x4 acc[4];
#pragma unroll
  for (int mf = 0; mf < 4; ++mf) acc[mf] = (f32x4){0.f, 0.f, 0.f, 0.f};

  auto ISSUE = [&](int iw, char* buf) {
    const int k0 = kbase + iw * BK;         // windows never straddle x/spk
    if (k0 < IN_F) {
      gload_lds16(xbt + (size_t)rA0 * IN_F + k0 + cswz, buf + s0 * 1024);
      gload_lds16(xbt + (size_t)rA1 * IN_F + k0 + cswz, buf + s1 * 1024);
    } else {
      const int kh = k0 - IN_F;
      gload_lds16(spkt + (size_t)rA0 * HID + kh + cswz, buf + s0 * 1024);
      gload_lds16(spkt + (size_t)rA1 * HID + kh + cswz, buf + s1 * 1024);
    }
    gload_lds16(w1hi + (size_t)(nbase + rA0) * TOTAL + k0 + cswz,
                buf + 8192 + s0 * 1024);
    gload_lds16(w1hi + (size_t)(nbase + rA1) * TOTAL + k0 + cswz,
                buf + 8192 + s1 * 1024);
    gload_lds16(w1lo + (size_t)(nbase + rA0) * TOTAL + k0 + cswz,
                buf + 16384 + s0 * 1024);
    gload_lds16(w1lo + (size_t)(nbase + rA1) * TOTAL + k0 + cswz,
                buf + 16384 + s1 * 1024);
  };

  auto COMP = [&](const char* buf) {
    const int browB = wv * 16 + fr;
#pragma unroll
    for (int s = 0; s < 2; ++s) {
      const int co = ((s * 4 + fks) ^ f7) * 16;
      bf16x8 bh = *(const bf16x8*)(buf + 8192  + browB * 128 + co);
      bf16x8 bl = *(const bf16x8*)(buf + 16384 + browB * 128 + co);
#pragma unroll
      for (int mf = 0; mf < 4; ++mf) {
        bf16x8 a = *(const bf16x8*)(buf + (mf * 16 + fr) * 128 + co);
        acc[mf] = __builtin_amdgcn_mfma_f32_16x16x32_bf16(a, bh, acc[mf], 0, 0, 0);
        acc[mf] = __builtin_amdgcn_mfma_f32_16x16x32_bf16(a, bl, acc[mf], 0, 0, 0);
      }
    }
  };

  ISSUE(0, smem);
  ISSUE(1, smem + BUFB);
  for (int i = 0; i < nwin; ++i) {
    if (i + 1 < nwin) {
      asm volatile("s_waitcnt vmcnt(6)" ::: "memory");
    } else {
      asm volatile("s_waitcnt vmcnt(0)" ::: "memory");
    }
    __builtin_amdgcn_s_barrier();
    asm volatile("" ::: "memory");
    const char* bufc = smem + (i % 3) * BUFB;
    COMP(bufc);
    if (i + 2 < nwin) ISSUE(i + 2, smem + ((i + 2) % 3) * BUFB);
  }

  float* pp = part + (size_t)ks * (BATCH * HID) + nbase + wv * 16 + fr;
  const int brow = (l >> 4) * 4;
#pragma unroll
  for (int mf = 0; mf < 4; ++mf) {
#pragma unroll
    for (int q = 0; q < 4; ++q) {
      pp[(size_t)(mf * 16 + brow + q) * HID] = acc[mf][q];
    }
  }
}

// ---------------- fc1 partial-reduce + LIF (fused; optional xcur seed) ----
__global__ __launch_bounds__(256)
void k_fc1_red(const float* __restrict__ part,   // [KSPL][B][HID]
               float* __restrict__ mem1,         // [B][HID]
               const float* __restrict__ beta,   // [HID]
               const float* __restrict__ thr,    // [HID]
               ushort* __restrict__ spk_out,     // [B][HID] bf16 bits
               const float* __restrict__ xc) {   // [B][HID] xcur slice | null
  const int i0 = (blockIdx.x * 256 + threadIdx.x) * 4;
  constexpr int PS = BATCH * HID;  // 262144
  float4 c;
  if (xc) {
    c = *(const float4*)(xc + i0);
  } else {
    c = make_float4(0.f, 0.f, 0.f, 0.f);
  }
#pragma unroll
  for (int k2 = 0; k2 < KSPL; ++k2) {
    const float4 p = *(const float4*)(part + (size_t)k2 * PS + i0);
    c.x += p.x; c.y += p.y; c.z += p.z; c.w += p.w;
  }

  const int n0 = i0 & (HID - 1);
  const float4 bt = *(const float4*)(beta + n0);
  const float4 th = *(const float4*)(thr + n0);
  float4 mv = *(float4*)(mem1 + i0);

  ushort4 so;
#define LIF1(COMP_M, COMP_B, COMP_T, SOUT)                  \
  {                                                         \
    float m2 = COMP_M - COMP_B + c.SOUT;                    \
    m2 = fmaxf(m2, 0.f);                                    \
    const bool sp = (m2 > COMP_T);                          \
    if (sp) m2 -= COMP_T;                                   \
    COMP_M = m2;                                            \
    so.SOUT = sp ? (ushort)0x3F80 : (ushort)0;              \
  }
  LIF1(mv.x, bt.x, th.x, x)
  LIF1(mv.y, bt.y, th.y, y)
  LIF1(mv.z, bt.z, th.z, z)
  LIF1(mv.w, bt.w, th.w, w)
#undef LIF1
  *(float4*)(mem1 + i0) = mv;
  *(ushort4*)(spk_out + i0) = so;
}

// ---------------- xcur GEMM: xcur = X @ w1x^T (parallel over T) ----------
// M = T*B = 8192, N = HID = 4096, K = IN_F = 1024. 8192 blocks, 256 thr,
// 64x64 tile, BK=64 double-buffered swizzled LDS (ro_gemm-v2 skeleton).
// Block decode keeps a 32-block group's A+B slices (~3MB) in one XCD L2.
__global__ __launch_bounds__(256, 2)
void k_xcur(const __hip_bfloat16* __restrict__ X,      // [8192][IN_F]
            const __hip_bfloat16* __restrict__ w1hi,   // [HID][TOTAL]
            const __hip_bfloat16* __restrict__ w1lo,
            float* __restrict__ xcur) {                // [8192][HID]
  __shared__ __align__(16) short lA[2][64 * BK];
  __shared__ __align__(16) short lBh[2][64 * BK];
  __shared__ __align__(16) short lBl[2][64 * BK];

  const int tid  = threadIdx.x;
  const int lane = tid & 63;
  const int w    = tid >> 6;

  // decode: xcd | gn (0..15) | gm (0..1) | wn (0..3) | wm (0..7)
  const int xcd = blockIdx.x & 7;
  const int c   = blockIdx.x >> 3;        // 0..1023
  const int w5  = c & 31;
  const int g   = c >> 5;                 // 0..31
  const int gm  = g & 1;
  const int gn  = g >> 1;                 // 0..15
  const int wm  = w5 & 7;
  const int wn  = w5 >> 3;                // 0..3
  const int mt  = xcd * 16 + gm * 8 + wm; // 0..127
  const int nt  = gn * 4 + wn;            // 0..63
  const int mbase = mt * 64;
  const int nbase = nt * 64;

  const int rS   = tid >> 2;
  const int cEl  = (tid & 3) * 16;
  const int swzX = (rS & 7) << 4;
  const int stByte0 = rS * 128 + ((cEl * 2) ^ swzX);
  const int stByte1 = rS * 128 + ((cEl * 2 + 16) ^ swzX);

  const int fr    = lane & 15;
  const int fkB   = (lane >> 4) * 16;
  const int frSwz = (fr & 7) << 4;

  f32x4 acc[4];
#pragma unroll
  for (int m = 0; m < 4; ++m) acc[m] = (f32x4){0.f, 0.f, 0.f, 0.f};
  bf16x8 rgA[6], rgB[6];

  auto GLOAD = [&](int it, bf16x8* R) {
    const int k0 = it * BK;
    const __hip_bfloat16* asrc = X    + (size_t)(mbase + rS) * IN_F  + k0 + cEl;
    const __hip_bfloat16* hsrc = w1hi + (size_t)(nbase + rS) * TOTAL + k0 + cEl;
    const __hip_bfloat16* lsrc = w1lo + (size_t)(nbase + rS) * TOTAL + k0 + cEl;
    R[0] = *(const bf16x8*)(asrc);
    R[1] = *(const bf16x8*)(asrc + 8);
    R[2] = *(const bf16x8*)(hsrc);
    R[3] = *(const bf16x8*)(hsrc + 8);
    R[4] = *(const bf16x8*)(lsrc);
    R[5] = *(const bf16x8*)(lsrc + 8);
  };
  auto DSWRITE = [&](int ibuf, bf16x8* R) {
    *(bf16x8*)((char*)lA[ibuf] + stByte0)  = R[0];
    *(bf16x8*)((char*)lA[ibuf] + stByte1)  = R[1];
    *(bf16x8*)((char*)lBh[ibuf] + stByte0) = R[2];
    *(bf16x8*)((char*)lBh[ibuf] + stByte1) = R[3];
    *(bf16x8*)((char*)lBl[ibuf] + stByte0) = R[4];
    *(bf16x8*)((char*)lBl[ibuf] + stByte1) = R[5];
  };
  auto COMPUTE = [&](int ibuf) {
    const char* pA  = (const char*)lA[ibuf];
    const char* pBh = (const char*)lBh[ibuf];
    const char* pBl = (const char*)lBl[ibuf];
#pragma unroll
    for (int s = 0; s < 2; ++s) {
      const int co = ((s * 64 + fkB) ^ frSwz);
      bf16x8 fbh = *(const bf16x8*)(pBh + (w * 16 + fr) * 128 + co);
      bf16x8 fbl = *(const bf16x8*)(pBl + (w * 16 + fr) * 128 + co);
#pragma unroll
      for (int m = 0; m < 4; ++m) {
        bf16x8 fa = *(const bf16x8*)(pA + (m * 16 + fr) * 128 + co);
        acc[m] = __builtin_amdgcn_mfma_f32_16x16x32_bf16(fa, fbh, acc[m], 0, 0, 0);
        acc[m] = __builtin_amdgcn_mfma_f32_16x16x32_bf16(fa, fbl, acc[m], 0, 0, 0);
      }
    }
  };

  constexpr int RNIT = IN_F / BK;  // 16
  GLOAD(0, rgA);
  DSWRITE(0, rgA);
  __syncthreads();
  for (int itp = 0; itp < RNIT / 2; ++itp) {
    const int it = itp * 2;
    GLOAD(it + 1, rgB);
    COMPUTE(0);
    DSWRITE(1, rgB);
    __syncthreads();
    if (it + 2 < RNIT) {
      GLOAD(it + 2, rgA);
      COMPUTE(1);
      DSWRITE(0, rgA);
      __syncthreads();
    } else {
      COMPUTE(1);
    }
  }

  const int col = nbase + w * 16 + fr;
  const int brow = (lane >> 4) * 4;
#pragma unroll
  for (int m = 0; m < 4; ++m) {
#pragma unroll
    for (int q = 0; q < 4; ++q) {
      const int row = mbase + m * 16 + brow + q;
      xcur[(size_t)row * HID + col] = acc[m][q];
    }
  }
}

// ---------------- readout GEMM v2 (unchanged) ----------------
__global__ __launch_bounds__(256, 2)
void k_ro_gemm(const __hip_bfloat16* __restrict__ A,
               const __hip_bfloat16* __restrict__ w2hi,
               const __hip_bfloat16* __restrict__ w2lo,
               const float* __restrict__ b2,
               float* __restrict__ cur2) {
  __shared__ __align__(16) short lA[2][64 * BK];
  __shared__ __align__(16) short lBh[2][64 * BK];
  __shared__ __align__(16) short lBl[2][64 * BK];

  const int tid  = threadIdx.x;
  const int lane = tid & 63;
  const int w    = tid >> 6;

  const int xcd = blockIdx.x & 7;
  const int c   = blockIdx.x >> 3;
  const int mt  = xcd * 16 + (c >> 3);
  const int nt  = c & 7;
  const int mbase = mt * 64;
  const int nbase = nt * 64;

  const int rS   = tid >> 2;
  const int cEl  = (tid & 3) * 16;
  const int swzX = (rS & 7) << 4;
  const int stByte0 = rS * 128 + ((cEl * 2) ^ swzX);
  const int stByte1 = rS * 128 + ((cEl * 2 + 16) ^ swzX);

  const int fr    = lane & 15;
  const int fkB   = (lane >> 4) * 16;
  const int frSwz = (fr & 7) << 4;

  f32x4 acc[4];
#pragma unroll
  for (int m = 0; m < 4; ++m) acc[m] = (f32x4){0.f, 0.f, 0.f, 0.f};
  bf16x8 rgA[6], rgB[6];

  auto GLOAD = [&](int it, bf16x8* R) {
    const int k0 = it * BK;
    const __hip_bfloat16* asrc = A    + (size_t)(mbase + rS) * HID + k0 + cEl;
    const __hip_bfloat16* hsrc = w2hi + (size_t)(nbase + rS) * HID + k0 + cEl;
    const __hip_bfloat16* lsrc = w2lo + (size_t)(nbase + rS) * HID + k0 + cEl;
    R[0] = *(const bf16x8*)(asrc);
    R[1] = *(const bf16x8*)(asrc + 8);
    R[2] = *(const bf16x8*)(hsrc);
    R[3] = *(const bf16x8*)(hsrc + 8);
    R[4] = *(const bf16x8*)(lsrc);
    R[5] = *(const bf16x8*)(lsrc + 8);
  };
  auto DSWRITE = [&](int ibuf, bf16x8* R) {
    *(bf16x8*)((char*)lA[ibuf] + stByte0)  = R[0];
    *(bf16x8*)((char*)lA[ibuf] + stByte1)  = R[1];
    *(bf16x8*)((char*)lBh[ibuf] + stByte0) = R[2];
    *(bf16x8*)((char*)lBh[ibuf] + stByte1) = R[3];
    *(bf16x8*)((char*)lBl[ibuf] + stByte0) = R[4];
    *(bf16x8*)((char*)lBl[ibuf] + stByte1) = R[5];
  };
  auto COMPUTE = [&](int ibuf) {
    const char* pA  = (const char*)lA[ibuf];
    const char* pBh = (const char*)lBh[ibuf];
    const char* pBl = (const char*)lBl[ibuf];
#pragma unroll
    for (int s = 0; s < 2; ++s) {
      const int co = ((s * 64 + fkB) ^ frSwz);
      bf16x8 fbh = *(const bf16x8*)(pBh + (w * 16 + fr) * 128 + co);
      bf16x8 fbl = *(const bf16x8*)(pBl + (w * 16 + fr) * 128 + co);
#pragma unroll
      for (int m = 0; m < 4; ++m) {
        bf16x8 fa = *(const bf16x8*)(pA + (m * 16 + fr) * 128 + co);
        acc[m] = __builtin_amdgcn_mfma_f32_16x16x32_bf16(fa, fbh, acc[m], 0, 0, 0);
        acc[m] = __builtin_amdgcn_mfma_f32_16x16x32_bf16(fa, fbl, acc[m], 0, 0, 0);
      }
    }
  };

  constexpr int RNIT = HID / BK;  // 64
  GLOAD(0, rgA);
  DSWRITE(0, rgA);
  __syncthreads();
  for (int itp = 0; itp < RNIT / 2; ++itp) {
    const int it = itp * 2;
    GLOAD(it + 1, rgB);
    COMPUTE(0);
    DSWRITE(1, rgB);
    __syncthreads();
    if (it + 2 < RNIT) {
      GLOAD(it + 2, rgA);
      COMPUTE(1);
      DSWRITE(0, rgA);
      __syncthreads();
    } else {
      COMPUTE(1);
    }
  }

  const int col = nbase + w * 16 + fr;
  const float bias = b2[col];
  const int brow = (lane >> 4) * 4;
#pragma unroll
  for (int m = 0; m < 4; ++m) {
#pragma unroll
    for (int q = 0; q < 4; ++q) {
      const int row = mbase + m * 16 + brow + q;
      cur2[(size_t)row * OUT_F + col] = acc[m][q] + bias;
    }
  }
}

// ---------------- readout LIF scan ----------------
__global__ void k_ro_scan(const float* __restrict__ cur2,
                          const float* __restrict__ beta,
                          const float* __restrict__ thr,
                          float* __restrict__ out) {
  const int i = blockIdx.x * blockDim.x + threadIdx.x;
  const int b = i >> 9;
  const int o = i & (OUT_F - 1);
  const float bt = beta[o];
  const float th = thr[o];
  float m = 0.0f;
  for (int t = 0; t < T_STEPS; ++t) {
    const size_t idx = (size_t)(t * BATCH + b) * OUT_F + o;
    m = m - bt + cur2[idx];
    const float s = (m > th) ? 1.0f : 0.0f;
    m -= s * th;
    out[idx] = s;
  }
}

// ---------------- launch ----------------
extern "C" void kernel_launch(void* const* d_in, const int* in_sizes, int n_in,
                              void* d_out, int out_size, void* d_ws, size_t ws_size,
                              hipStream_t stream) {
  const float* x        = (const float*)d_in[0];
  const float* w1       = (const float*)d_in[1];
  const float* w2       = (const float*)d_in[2];
  const float* b2       = (const float*)d_in[3];
  const float* beta_lsm = (const float*)d_in[4];
  const float* thr_lsm  = (const float*)d_in[5];
  const float* beta_ro  = (const float*)d_in[6];
  const float* thr_ro   = (const float*)d_in[7];
  float* out = (float*)d_out;

  char* ws = (char*)d_ws;
  size_t off = 0;
  auto alloc = [&](size_t bytes) -> char* {
    char* p = ws + off;
    off += (bytes + 255) & ~(size_t)255;
    return p;
  };
  __hip_bfloat16* w1hi = (__hip_bfloat16*)alloc((size_t)HID * TOTAL * 2);
  __hip_bfloat16* w1lo = (__hip_bfloat16*)alloc((size_t)HID * TOTAL * 2);
  __hip_bfloat16* xb   = (__hip_bfloat16*)alloc((size_t)T_STEPS * BATCH * IN_F * 2);
  __hip_bfloat16* spk  = (__hip_bfloat16*)alloc((size_t)(T_STEPS + 1) * BATCH * HID * 2);
  __hip_bfloat16* w2hi = (__hip_bfloat16*)alloc((size_t)OUT_F * HID * 2);
  __hip_bfloat16* w2lo = (__hip_bfloat16*)alloc((size_t)OUT_F * HID * 2);
  float* mem1 = (float*)alloc((size_t)BATCH * HID * 4);
  float* cur2 = (float*)alloc((size_t)T_STEPS * BATCH * OUT_F * 4);
  float* part = cur2;   // aliased, disjoint lifetimes (steps vs readout)

  // xcur (134MB) only if ws allows; else exact r9 fallback path.
  const size_t xcur_bytes = (size_t)T_STEPS * BATCH * HID * 4;
  float* xcur = nullptr;
  if (off + xcur_bytes <= ws_size) {
    xcur = (float*)alloc(xcur_bytes);
  }

  // prep
  {
    int n4 = HID * TOTAL / 4;
    k_cvt_split<<<(n4 + 255) / 256, 256, 0, stream>>>(w1, w1hi, w1lo, n4);
  }
  {
    int n4 = OUT_F * HID / 4;
    k_cvt_split<<<(n4 + 255) / 256, 256, 0, stream>>>(w2, w2hi, w2lo, n4);
  }
  {
    int n = T_STEPS * BATCH * IN_F;
    k_cvt_x<<<(n + 255) / 256, 256, 0, stream>>>(x, xb, n);
  }
  {
    int n = BATCH * HID;
    k_zero<<<(n + 255) / 256, 256, 0, stream>>>(mem1, (ushort*)spk, n);
  }

  if (xcur) {
    // parallel-T x-contribution GEMM (one-time)
    k_xcur<<<(T_STEPS * BATCH / 64) * (HID / 64), 256, 0, stream>>>(
        xb, w1hi, w1lo, xcur);
    // steps: recurrent K=4096 only (w1h 67MB/step), xcur-seeded reduce
    for (int t = 0; t < T_STEPS; ++t) {
      k_fc1<<<NCH * KSPL, 256, 0, stream>>>(t, xb, spk, w1hi, w1lo, part,
                                            HID / KSPL, HID / KSPL / BK, IN_F);
      k_fc1_red<<<BATCH * HID / (256 * 4), 256, 0, stream>>>(
          part, mem1, beta_lsm, thr_lsm,
          (ushort*)(spk + (size_t)(t + 1) * BATCH * HID),
          xcur + (size_t)t * BATCH * HID);
    }
  } else {
    // fallback: r9 exact path (K=5120 per step)
    for (int t = 0; t < T_STEPS; ++t) {
      k_fc1<<<NCH * KSPL, 256, 0, stream>>>(t, xb, spk, w1hi, w1lo, part,
                                            TOTAL / KSPL, TOTAL / KSPL / BK, 0);
      k_fc1_red<<<BATCH * HID / (256 * 4), 256, 0, stream>>>(
          part, mem1, beta_lsm, thr_lsm,
          (ushort*)(spk + (size_t)(t + 1) * BATCH * HID), nullptr);
    }
  }

  // readout
  k_ro_gemm<<<(T_STEPS * BATCH / 64) * (OUT_F / 64), 256, 0, stream>>>(
      spk + (size_t)BATCH * HID, w2hi, w2lo, b2, cur2);
  k_ro_scan<<<(BATCH * OUT_F) / 256, 256, 0, stream>>>(cur2, beta_ro, thr_ro, out);
}